// Round 2
// baseline (2166.589 us; speedup 1.0000x reference)
//
#include <hip/hip_runtime.h>
#include <hip/hip_bf16.h>

#define BATCH 16384
#define DIM   64
#define NNB   32
#define INDIM 4096          // 2 * NNB * DIM
#define RPB   4             // batch rows per block

typedef __attribute__((ext_vector_type(8))) unsigned short us8;

__device__ __forceinline__ float bf2f(unsigned short u) {
    union { unsigned int i; float f; } v;
    v.i = ((unsigned int)u) << 16;
    return v.f;
}

template<bool FP32>
__device__ __forceinline__ float ldT(const void* p, size_t i) {
    if constexpr (FP32) return ((const float*)p)[i];
    else                return bf2f(((const unsigned short*)p)[i]);
}

// ws layout: [0:8) double loss accumulator, [8:12) int dtype flag (1=fp32, 0=bf16)
__global__ void kgnn_probe(const unsigned int* __restrict__ lab, int* __restrict__ flag) {
    if (threadIdx.x == 0) {
        int ok = 1;
        for (int i = 0; i < 32; ++i) {
            unsigned int w = lab[i];
            if (!(w == 0u || w == 0x3F800000u)) ok = 0;   // exactly 0.0f or 1.0f
        }
        *flag = ok;   // all-clean fp32 words -> fp32 problem; else bf16
    }
}

// Scalar (non-MFMA) reference-grade kernel. Block = 256 threads = 4 waves;
// wave r owns batch row base+r; lane d owns output dim d.
template<bool FP32>
__global__ void kgnn_scalar(
    const int* __restrict__ users, const int* __restrict__ items,
    const void* __restrict__ label_, const int* __restrict__ nrel,
    const int* __restrict__ ntail,  const void* __restrict__ uemb_,
    const void* __restrict__ eemb_, const void* __restrict__ remb_,
    const void* __restrict__ W_,    const void* __restrict__ b_,
    double* __restrict__ acc, const int* __restrict__ flag)
{
    if (*flag != (FP32 ? 1 : 0)) return;   // uniform: wrong-dtype variant exits early

    __shared__ int   nidx[RPB][2][NNB];    // [row][rel/tail][neighbor]
    __shared__ float trs[RPB][INDIM];      // t_r rows, fp32-converted (64 KB)

    const int t    = threadIdx.x;
    const int base = blockIdx.x * RPB;

    {   // stage neighbor indices: 4 rows * 64 ints = 256 = blockDim
        const int r = t >> 6, rem = t & 63, half = rem >> 5, n = rem & 31;
        const int row = base + r;
        nidx[r][half][n] = half ? ntail[row * NNB + n] : nrel[row * NNB + n];
    }
    __syncthreads();

    // stage t_r: element e -> row r, k; k -> neighbor n, rel/tail half, dim j
    #pragma unroll
    for (int it = 0; it < RPB * INDIM / 256; ++it) {
        const int e = it * 256 + t;
        const int r = e >> 12, k = e & 4095;
        const int n = k >> 7, half = (k >> 6) & 1, j = k & 63;
        const int idx = nidx[r][half][n];
        const void* tbl = half ? eemb_ : remb_;
        trs[r][k] = ldT<FP32>(tbl, (size_t)idx * DIM + j);
    }
    __syncthreads();

    const int r = t >> 6;     // row within tile == wave id
    const int d = t & 63;     // output dim == lane id

    // false_logit[d] = sum_k t_r[k] * gen_W[d][k]
    float s = 0.f;
    if constexpr (FP32) {
        const float4* wp = (const float4*)((const float*)W_ + (size_t)d * INDIM);
        for (int k4 = 0; k4 < INDIM / 4; ++k4) {
            const float4 w = wp[k4];
            const float* trp = &trs[r][k4 * 4];
            s += w.x * trp[0] + w.y * trp[1] + w.z * trp[2] + w.w * trp[3];
        }
    } else {
        const us8* wp = (const us8*)((const unsigned short*)W_ + (size_t)d * INDIM);
        for (int k8 = 0; k8 < INDIM / 8; ++k8) {
            const us8 w = wp[k8];
            const float* trp = &trs[r][k8 * 8];
            #pragma unroll
            for (int j = 0; j < 8; ++j) s += bf2f(w[j]) * trp[j];
        }
    }
    const float fi = 1.f / (1.f + expf(-(s + ldT<FP32>(b_, d))));  // false_item[d]

    const int row = base + r;
    const int uid = users[row], iid = items[row];
    const float u  = ldT<FP32>(uemb_, (size_t)uid * DIM + d);
    const float iv = ldT<FP32>(eemb_, (size_t)iid * DIM + d);
    float p1 = u * iv;    // -> predict logit
    float p2 = u * fi;    // -> false_predict logit
    #pragma unroll
    for (int m = 1; m < 64; m <<= 1) {
        p1 += __shfl_xor(p1, m, 64);
        p2 += __shfl_xor(p2, m, 64);
    }
    if (d == 0) {
        const float y  = ldT<FP32>(label_, row);
        const float pa = 1.f / (1.f + expf(-p1));
        const float pb = 1.f / (1.f + expf(-p2));
        const float term =
              y * fmaxf(logf(pa), -100.f) + (1.f - y) * fmaxf(log1pf(-pa), -100.f)
            + y * fmaxf(logf(pb), -100.f) + (1.f - y) * fmaxf(log1pf(-pb), -100.f);
        atomicAdd(acc, (double)term);
    }
}

__global__ void kgnn_fin(const double* __restrict__ acc,
                         const int* __restrict__ flag, void* __restrict__ out) {
    if (threadIdx.x == 0 && blockIdx.x == 0) {
        const float loss = (float)(-(*acc) / (double)BATCH);
        if (*flag) ((float*)out)[0] = loss;
        else       ((__hip_bfloat16*)out)[0] = __float2bfloat16(loss);
    }
}

extern "C" void kernel_launch(void* const* d_in, const int* in_sizes, int n_in,
                              void* d_out, int out_size, void* d_ws, size_t ws_size,
                              hipStream_t stream) {
    const int* users = (const int*)d_in[0];
    const int* items = (const int*)d_in[1];
    const void* label = d_in[2];
    const int* nrel  = (const int*)d_in[3];
    const int* ntail = (const int*)d_in[4];
    const void* uemb = d_in[5];
    const void* eemb = d_in[6];
    const void* remb = d_in[7];
    const void* genW = d_in[8];
    const void* genb = d_in[9];

    double* acc = (double*)d_ws;
    int* flag   = (int*)((char*)d_ws + 8);
    hipMemsetAsync(d_ws, 0, 16, stream);

    kgnn_probe<<<1, 64, 0, stream>>>((const unsigned int*)label, flag);

    kgnn_scalar<false><<<BATCH / RPB, 256, 0, stream>>>(
        users, items, label, nrel, ntail, uemb, eemb, remb, genW, genb, acc, flag);
    kgnn_scalar<true><<<BATCH / RPB, 256, 0, stream>>>(
        users, items, label, nrel, ntail, uemb, eemb, remb, genW, genb, acc, flag);

    kgnn_fin<<<1, 64, 0, stream>>>(acc, flag, d_out);
}